// Round 4
// baseline (1551.011 us; speedup 1.0000x reference)
//
#include <hip/hip_runtime.h>
#include <hip/hip_bf16.h>

typedef __hip_bfloat16 bf16;

__device__ __forceinline__ float b2f(bf16 v) { return __bfloat162float(v); }
__device__ __forceinline__ bf16 f2b(float v) { return __float2bfloat16(v); }

__device__ __forceinline__ float ldv(const void* p, size_t i, bool f32) {
    return f32 ? ((const float*)p)[i] : b2f(((const bf16*)p)[i]);
}

// ---------------- K-1: dtype detector (unchanged, proven) ----------------
__global__ void k_detect(const void* x, int* flag) {
    __shared__ int cnt;
    if (threadIdx.x == 0) cnt = 0;
    __syncthreads();
    const unsigned short* us = (const unsigned short*)x;
    int local = 0;
    for (int i = threadIdx.x; i < 8192; i += 256) {
        unsigned e = us[2 * i] & 0x7F80u;
        if (e == 0x7F80u || e == 0u) local++;
    }
    atomicAdd(&cnt, local);
    __syncthreads();
    if (threadIdx.x == 0) flag[0] = (cnt >= 8) ? 1 : 0;
}

// ---------------- K0: weight prep ----------------
__global__ void k_prep(const void* gw, const void* gb, const void* tw, const void* tb,
                       const void* pw, const void* pb, const void* ww, const void* wb,
                       const void* cw, const void* bng, const void* bnb,
                       const void* bnm, const void* bnv, const int* flag,
                       float* __restrict__ wtgp, float* __restrict__ btgp,
                       float* __restrict__ wwT, float* __restrict__ wbf,
                       float* __restrict__ wfold, float* __restrict__ bfold)
{
    bool f32 = flag[0] != 0;
    int gid = blockIdx.x * 256 + threadIdx.x;
    int stride = gridDim.x * 256;
    // wtgp[k][96]: k = 0..63 input channel; cols [theta 0..31 | g 32..63 | phi 64..95]
    for (int e = gid; e < 64 * 96; e += stride) {
        int k = e / 96, c = e % 96;
        float v;
        if (c < 32)      v = ldv(tw, (size_t)c * 64 + k, f32);
        else if (c < 64) v = ldv(gw, (size_t)(c - 32) * 64 + k, f32);
        else             v = ldv(pw, (size_t)(c - 64) * 64 + k, f32);
        wtgp[e] = v;
    }
    for (int e = gid; e < 96; e += stride) {
        float v = (e < 32) ? ldv(tb, e, f32)
                           : (e < 64 ? ldv(gb, e - 32, f32) : ldv(pb, e - 64, f32));
        btgp[e] = v;
    }
    for (int e = gid; e < 32 * 64; e += stride) {
        int c = e / 64, o = e % 64;
        wwT[e] = ldv(ww, (size_t)o * 32 + c, f32);
    }
    for (int e = gid; e < 64; e += stride) wbf[e] = ldv(wb, e, f32);
    for (int e = gid; e < 64 * 9 * 32; e += stride) {
        int c = e / 288, r = e % 288, tap = r / 32, o = r % 32;
        float inv = ldv(bng, o, f32) * rsqrtf(ldv(bnv, o, f32) + 1e-5f);
        wfold[e] = ldv(cw, ((size_t)o * 64 + c) * 9 + tap, f32) * inv;
    }
    for (int e = gid; e < 32; e += stride) {
        float inv = ldv(bng, e, f32) * rsqrtf(ldv(bnv, e, f32) + 1e-5f);
        bfold[e] = ldv(bnb, e, f32) - ldv(bnm, e, f32) * inv;
    }
}

// ---------------- K1: fused theta/g/phi 1x1 conv, thread per pixel ----------------
__global__ void k_tgp(const void* f1, const void* f2, const int* flag,
                      const float* __restrict__ wtgp, const float* __restrict__ btgp,
                      bf16* __restrict__ theta, bf16* __restrict__ gfull,
                      bf16* __restrict__ pfull, int N)
{
    bool f32 = flag[0] != 0;
    int gid = blockIdx.x * 256 + threadIdx.x;
    int b = gid / N;
    int ii = gid - b * N;
    float acc[96];
#pragma unroll
    for (int c = 0; c < 96; c++) acc[c] = btgp[c];
    size_t base = (size_t)b * 32 * N + ii;
    for (int k = 0; k < 32; k++) {
        float xv = ldv(f1, base + (size_t)k * N, f32);
        const float* w = wtgp + k * 96;
#pragma unroll
        for (int c = 0; c < 96; c++) acc[c] += xv * w[c];
    }
    for (int k = 0; k < 32; k++) {
        float xv = ldv(f2, base + (size_t)k * N, f32);
        const float* w = wtgp + (k + 32) * 96;
#pragma unroll
        for (int c = 0; c < 96; c++) acc[c] += xv * w[c];
    }
    bf16* tp = theta + (size_t)gid * 32;
    bf16* gp = gfull + (size_t)gid * 32;
    bf16* pp = pfull + (size_t)gid * 32;
#pragma unroll
    for (int c = 0; c < 32; c++) tp[c] = f2b(acc[c]);
#pragma unroll
    for (int c = 0; c < 32; c++) gp[c] = f2b(acc[32 + c]);
#pragma unroll
    for (int c = 0; c < 32; c++) pp[c] = f2b(acc[64 + c]);
}

// ---------------- K2: max pool -> interleaved fp32 pg[j][64] = [phi 0..31 | g 32..63] ----------------
__global__ void k_pool(const bf16* __restrict__ gfull, const bf16* __restrict__ pfull,
                       float* __restrict__ pg, int n, int W, int s, int wp, int total)
{
    int gid = blockIdx.x * 256 + threadIdx.x;
    if (gid >= total) return;
    int c = gid & 63;
    int j = (gid >> 6) % n;
    int b = gid / (64 * n);
    int py = j / wp, px = j % wp;
    const int N = W * W;
    const bf16* src = (c < 32) ? pfull : gfull;   // phi first, then g
    int ch = c & 31;
    float mv = -INFINITY;
    for (int dy = 0; dy < s; dy++)
        for (int dx = 0; dx < s; dx++) {
            int idx = (py * s + dy) * W + px * s + dx;
            mv = fmaxf(mv, b2f(src[((size_t)b * N + idx) * 32 + ch]));
        }
    pg[((size_t)b * n + j) * 64 + c] = mv;
}

// ---------------- K3: attention (no online max: scores bounded) + W-conv + residual ----------------
// Block = 64 pixels x 8 waves; wave wv owns j-chunk [n*wv/8, n*(wv+1)/8).
// pg rows are wave-uniform fp32 -> scalar loads; inner loop is pure FMA + exp.
__launch_bounds__(512)
__global__ void k_attn_fused(const bf16* __restrict__ theta, const float* __restrict__ pg,
                             const void* f1, const void* f2, const int* flag,
                             const float* __restrict__ wwT, const float* __restrict__ wbf,
                             bf16* __restrict__ z, int N, int n)
{
    bool f32 = flag[0] != 0;
    __shared__ float sl[8][64];
    __shared__ bf16 sy[8][64 * 33];
    int tid = threadIdx.x;
    int lane = tid & 63;
    int wv = tid >> 6;
    int row0 = blockIdx.x * 64;        // N % 64 == 0 -> block within one batch image
    int b = row0 / N;
    int ii = (row0 - b * N) + lane;
    int bn = b * n;

    // this lane's theta row (precomputed, bf16)
    const bf16* th = theta + (size_t)(row0 + lane) * 32;
    float t[32];
#pragma unroll
    for (int c = 0; c < 32; c++) t[c] = b2f(th[c]);

    int js = (n * wv) >> 3;
    int je = (n * (wv + 1)) >> 3;
    float l = 0.f;
    float acc[32];
#pragma unroll
    for (int c = 0; c < 32; c++) acc[c] = 0.f;

    for (int j = js; j < je; j++) {
        const float* pr = pg + (size_t)(bn + j) * 64;   // uniform address
        float f = 0.f;
#pragma unroll
        for (int c = 0; c < 32; c++) f += t[c] * pr[c];          // phi
        float p = __expf(f);                                      // scores bounded ~|10|
        l += p;
#pragma unroll
        for (int c = 0; c < 32; c++) acc[c] += p * pr[32 + c];    // g
    }

    sl[wv][lane] = l;
#pragma unroll
    for (int c = 0; c < 32; c++) sy[wv][lane * 33 + c] = f2b(acc[c]);
    __syncthreads();

    // merge: plain sum over 8 partials, normalize; y -> sy[0]
    {
        int r = tid >> 3, c0 = (tid & 7) * 4;
        float L = 0.f;
#pragma unroll
        for (int w = 0; w < 8; w++) L += sl[w][r];
        float invL = 1.f / L;
#pragma unroll
        for (int cc = 0; cc < 4; cc++) {
            int idx = r * 33 + c0 + cc;
            float v = 0.f;
#pragma unroll
            for (int w = 0; w < 8; w++) v += b2f(sy[w][idx]);
            sy[0][idx] = f2b(v * invL);
        }
    }
    __syncthreads();

    // epilogue: z[o][pixel] = wwT*y + wbf + x ; wave wv owns o in [8wv, 8wv+8)
    float yrow[32];
#pragma unroll
    for (int c = 0; c < 32; c++) yrow[c] = b2f(sy[0][lane * 33 + c]);
    int o0 = wv * 8;
    const void* fx = (o0 < 32) ? f1 : f2;
    for (int oo = 0; oo < 8; oo++) {
        int o = o0 + oo;
        int op = o & 31;
        float a = wbf[o];
        const float* w = wwT + o;          // wwT[c*64+o], uniform scalar loads
#pragma unroll
        for (int c = 0; c < 32; c++) a += yrow[c] * w[c * 64];
        a += ldv(fx, (size_t)(b * 32 + op) * N + ii, f32);
        z[((size_t)(b * 64 + o)) * N + ii] = f2b(a);
    }
}

// ---------------- K5: 3x3 conv (64->32) + folded BN (unchanged, proven) ----------------
__launch_bounds__(256)
__global__ void k_conv3(const bf16* __restrict__ z, const float* __restrict__ wfold,
                        const float* __restrict__ bfold, void* out, size_t outOff,
                        const int* flag, int H, int tX)
{
    bool f32 = flag[0] != 0;
    __shared__ float zs[16 * 324];
    const int W = H, Npix = H * W;
    int tid = threadIdx.x;
    int tilesPerImg = tX * tX;
    int b = blockIdx.x / tilesPerImg;
    int t = blockIdx.x % tilesPerImg;
    int ty = t / tX, tx = t % tX;
    int ly = tid >> 4, lx = tid & 15;
    int oy = ty * 16 + ly, ox = tx * 16 + lx;
    bool act = (oy < H) && (ox < W);
    float acc[32];
#pragma unroll
    for (int o = 0; o < 32; o++) acc[o] = 0.f;

    for (int cc = 0; cc < 4; cc++) {
        __syncthreads();
        for (int e = tid; e < 16 * 324; e += 256) {
            int c = e / 324, r = e % 324, yy = r / 18, xx = r % 18;
            int gy = ty * 16 - 1 + yy, gx = tx * 16 - 1 + xx;
            float v = 0.f;
            if (gy >= 0 && gy < H && gx >= 0 && gx < W)
                v = b2f(z[((size_t)(b * 64 + cc * 16 + c)) * Npix + gy * W + gx]);
            zs[e] = v;
        }
        __syncthreads();
        if (act) {
            for (int c = 0; c < 16; c++) {
#pragma unroll
                for (int dy = 0; dy < 3; dy++)
#pragma unroll
                    for (int dx = 0; dx < 3; dx++) {
                        float zv = zs[c * 324 + (ly + dy) * 18 + (lx + dx)];
                        const float* w = wfold + ((size_t)(cc * 16 + c) * 9 + dy * 3 + dx) * 32;
#pragma unroll
                        for (int o = 0; o < 32; o++) acc[o] += zv * w[o];
                    }
            }
        }
    }
    if (act) {
        size_t ob = outOff + (size_t)b * 32 * Npix + (size_t)oy * W + ox;
        if (f32) {
            float* op = (float*)out;
#pragma unroll
            for (int o = 0; o < 32; o++) op[ob + (size_t)o * Npix] = acc[o] + bfold[o];
        } else {
            bf16* op = (bf16*)out;
#pragma unroll
            for (int o = 0; o < 32; o++) op[ob + (size_t)o * Npix] = f2b(acc[o] + bfold[o]);
        }
    }
}

extern "C" void kernel_launch(void* const* d_in, const int* in_sizes, int n_in,
                              void* d_out, int out_size, void* d_ws, size_t ws_size,
                              hipStream_t stream)
{
    const int B = 4;
    const int Hs[3] = {96, 48, 24};
    const int ss[3] = {2, 4, 8};
    const size_t outOff[3] = {0, 1179648, 1474560};

    int* flag = (int*)d_ws;
    float* wsf = (float*)d_ws + 16;
    // fp32 weights (26880 floats)
    size_t o_wtgp = 0, o_btgp = 6144, o_wwT = 6272, o_wbf = 8320;
    size_t o_wfold = 8384, o_bfold = 26816;             // end 26880
    // fp32 pooled pg[j][64], max B*n = 9216 rows
    size_t o_pg = 26880;                                // 589,824 floats -> end 616,704
    // bf16 region: [theta | gfull | pfull]; z (BN*64) overlays gfull+pfull
    bf16* bb = (bf16*)(wsf + 616704);
    const size_t BN1 = (size_t)B * 9216;
    size_t o_th = 0;
    size_t o_g = o_th + BN1 * 32;
    size_t o_p = o_g + BN1 * 32;
    // total ws ~ 9.6 MB

    k_detect<<<1, 256, 0, stream>>>(d_in[0], flag);

    for (int lv = 0; lv < 3; lv++) {
        int H = Hs[lv], W = H, N = H * W, s = ss[lv];
        int wp = W / s, n = wp * wp;
        const void* f1 = d_in[2 * lv];
        const void* f2 = d_in[2 * lv + 1];
        const int wb0 = 6 + 13 * lv;
        k_prep<<<32, 256, 0, stream>>>(d_in[wb0 + 0], d_in[wb0 + 1], d_in[wb0 + 2],
                                       d_in[wb0 + 3], d_in[wb0 + 4], d_in[wb0 + 5],
                                       d_in[wb0 + 6], d_in[wb0 + 7], d_in[wb0 + 8],
                                       d_in[wb0 + 9], d_in[wb0 + 10], d_in[wb0 + 11],
                                       d_in[wb0 + 12], flag,
                                       wsf + o_wtgp, wsf + o_btgp, wsf + o_wwT,
                                       wsf + o_wbf, wsf + o_wfold, wsf + o_bfold);
        int BN = B * N;
        k_tgp<<<BN / 256, 256, 0, stream>>>(f1, f2, flag, wsf + o_wtgp, wsf + o_btgp,
                                            bb + o_th, bb + o_g, bb + o_p, N);
        int tot = B * n * 64;
        k_pool<<<(tot + 255) / 256, 256, 0, stream>>>(bb + o_g, bb + o_p,
                                                      wsf + o_pg, n, W, s, wp, tot);
        k_attn_fused<<<BN / 64, 512, 0, stream>>>(bb + o_th, wsf + o_pg,
                                                  f1, f2, flag,
                                                  wsf + o_wwT, wsf + o_wbf,
                                                  bb + o_g, N, n);   // z overlays g/p
        int tX = (H + 15) / 16;
        k_conv3<<<B * tX * tX, 256, 0, stream>>>(bb + o_g, wsf + o_wfold, wsf + o_bfold,
                                                 d_out, outOff[lv], flag, H, tX);
    }
}

// Round 5
// 733.304 us; speedup vs baseline: 2.1151x; 2.1151x over previous
//
#include <hip/hip_runtime.h>
#include <hip/hip_bf16.h>

typedef __hip_bfloat16 bf16;
typedef __attribute__((ext_vector_type(8))) short short8;
typedef __attribute__((ext_vector_type(4))) float floatx4;

__device__ __forceinline__ float b2f(bf16 v) { return __bfloat162float(v); }
__device__ __forceinline__ bf16 f2b(float v) { return __float2bfloat16(v); }
__device__ __forceinline__ float ldv(const void* p, size_t i, bool f32) {
    return f32 ? ((const float*)p)[i] : b2f(((const bf16*)p)[i]);
}
#define MFMA16(a, b, c) __builtin_amdgcn_mfma_f32_16x16x32_bf16(a, b, c, 0, 0, 0)

struct Ptrs { const void* p[45]; };

// ---------------- K-1: dtype detector (proven) ----------------
__global__ void k_detect(const void* x, int* flag) {
    __shared__ int cnt;
    if (threadIdx.x == 0) cnt = 0;
    __syncthreads();
    const unsigned short* us = (const unsigned short*)x;
    int local = 0;
    for (int i = threadIdx.x; i < 8192; i += 256) {
        unsigned e = us[2 * i] & 0x7F80u;
        if (e == 0x7F80u || e == 0u) local++;
    }
    atomicAdd(&cnt, local);
    __syncthreads();
    if (threadIdx.x == 0) flag[0] = (cnt >= 8) ? 1 : 0;
}

// per-level weight region layout (float offsets), stride LVS
#define O_WTGP  0
#define O_BTGP  6144
#define O_WBF   6240
#define O_BFOLD 6304
#define O_WFOLD 6336
#define O_WT    24768
#define LVS     25856

// ---------------- K0: fused weight prep, all 3 levels in one launch ----------------
__global__ void k_prep(Ptrs in, const int* flag, float* __restrict__ wsf)
{
    int lv = blockIdx.y;
    float* base = wsf + (size_t)lv * LVS;
    const int wb0 = 6 + 13 * lv;
    const void* gw  = in.p[wb0 + 0];
    const void* gb  = in.p[wb0 + 1];
    const void* tw  = in.p[wb0 + 2];
    const void* tb  = in.p[wb0 + 3];
    const void* pw  = in.p[wb0 + 4];
    const void* pb  = in.p[wb0 + 5];
    const void* ww  = in.p[wb0 + 6];
    const void* wb  = in.p[wb0 + 7];
    const void* cw  = in.p[wb0 + 8];
    const void* bng = in.p[wb0 + 9];
    const void* bnb = in.p[wb0 + 10];
    const void* bnm = in.p[wb0 + 11];
    const void* bnv = in.p[wb0 + 12];
    bool f32 = flag[0] != 0;
    int gid = blockIdx.x * 256 + threadIdx.x;
    int stride = gridDim.x * 256;

    float* wtgp = base + O_WTGP;
    float* btgp = base + O_BTGP;
    float* wbf = base + O_WBF;
    float* bfold = base + O_BFOLD;
    float* wfold = base + O_WFOLD;
    bf16* Wt = (bf16*)(base + O_WT);

    // wtgp[k][96]: cols [theta 0..31 | g 32..63 | phi 64..95]
    for (int e = gid; e < 64 * 96; e += stride) {
        int k = e / 96, c = e % 96;
        float v;
        if (c < 32)      v = ldv(tw, (size_t)c * 64 + k, f32);
        else if (c < 64) v = ldv(gw, (size_t)(c - 32) * 64 + k, f32);
        else             v = ldv(pw, (size_t)(c - 64) * 64 + k, f32);
        wtgp[e] = v;
    }
    for (int e = gid; e < 96; e += stride) {
        float v = (e < 32) ? ldv(tb, e, f32)
                           : (e < 64 ? ldv(gb, e - 32, f32) : ldv(pb, e - 64, f32));
        btgp[e] = v;
    }
    // Wt[o][c] bf16 for MFMA W-conv (B-frag reads contiguous in c)
    for (int e = gid; e < 64 * 32; e += stride)
        Wt[e] = f2b(ldv(ww, e, f32));
    for (int e = gid; e < 64; e += stride) wbf[e] = ldv(wb, e, f32);
    for (int e = gid; e < 64 * 9 * 32; e += stride) {
        int c = e / 288, r = e % 288, tap = r / 32, o = r % 32;
        float inv = ldv(bng, o, f32) * rsqrtf(ldv(bnv, o, f32) + 1e-5f);
        wfold[e] = ldv(cw, ((size_t)o * 64 + c) * 9 + tap, f32) * inv;
    }
    for (int e = gid; e < 32; e += stride) {
        float inv = ldv(bng, e, f32) * rsqrtf(ldv(bnv, e, f32) + 1e-5f);
        bfold[e] = ldv(bnb, e, f32) - ldv(bnm, e, f32) * inv;
    }
}

// ---------------- K1: theta/g/phi 1x1 conv; blockIdx.y = output group ----------------
__global__ void k_tgp(const void* f1, const void* f2, const int* flag,
                      const float* __restrict__ wtgp, const float* __restrict__ btgp,
                      bf16* __restrict__ theta, bf16* __restrict__ gfull,
                      bf16* __restrict__ pfull, int N)
{
    bool f32 = flag[0] != 0;
    int grp = blockIdx.y;                    // 0=theta 1=g 2=phi
    bf16* dst = (grp == 0) ? theta : ((grp == 1) ? gfull : pfull);
    int co = grp * 32;
    int gid = blockIdx.x * 256 + threadIdx.x;
    int b = gid / N;
    int ii = gid - b * N;
    float acc[32];
#pragma unroll
    for (int c = 0; c < 32; c++) acc[c] = btgp[co + c];
    size_t base = (size_t)b * 32 * N + ii;
    for (int k = 0; k < 32; k++) {
        float xv = ldv(f1, base + (size_t)k * N, f32);
        const float* w = wtgp + k * 96 + co;
#pragma unroll
        for (int c = 0; c < 32; c++) acc[c] += xv * w[c];
    }
    for (int k = 0; k < 32; k++) {
        float xv = ldv(f2, base + (size_t)k * N, f32);
        const float* w = wtgp + (k + 32) * 96 + co;
#pragma unroll
        for (int c = 0; c < 32; c++) acc[c] += xv * w[c];
    }
    bf16* dp = dst + (size_t)gid * 32;
#pragma unroll
    for (int c = 0; c < 32; c++) dp[c] = f2b(acc[c]);
}

// ---------------- K2: max pool -> phiB[b][npad][32] and gT[b][32][npad], zero-padded ----------------
__global__ void k_pool(const bf16* __restrict__ gfull, const bf16* __restrict__ pfull,
                       bf16* __restrict__ phiB, bf16* __restrict__ gT,
                       int n, int npad, int W, int s, int wp, int total)
{
    int gid = blockIdx.x * 256 + threadIdx.x;
    if (gid >= total) return;
    int c = gid & 31;
    int j = (gid >> 5) % npad;
    int b = gid / (32 * npad);
    float mg = 0.f, mp = 0.f;
    if (j < n) {
        int py = j / wp, px = j % wp;
        const int N = W * W;
        mg = -INFINITY; mp = -INFINITY;
        for (int dy = 0; dy < s; dy++)
            for (int dx = 0; dx < s; dx++) {
                int idx = (py * s + dy) * W + px * s + dx;
                size_t bse = ((size_t)b * N + idx) * 32 + c;
                mg = fmaxf(mg, b2f(gfull[bse]));
                mp = fmaxf(mp, b2f(pfull[bse]));
            }
    }
    phiB[((size_t)b * npad + j) * 32 + c] = f2b(mp);
    gT[((size_t)b * 32 + c) * npad + j] = f2b(mg);
}

// ---------------- K3: MFMA attention + W-conv + residual ----------------
// Block = 64 query pixels, 4 waves; wave owns 16 rows, loops all keys.
// mfma_f32_16x16x32_bf16: A[m=lane&15][k=quad*8+j], B[k=quad*8+j][n=lane&15],
// C/D: col=lane&15, row=quad*4+reg.  Padded keys (phi=0,g=0) give exp(0)=1 -> l -= npad-n.
__launch_bounds__(256)
__global__ void k_attn_mfma(const bf16* __restrict__ theta, const bf16* __restrict__ phiB,
                            const bf16* __restrict__ gT,
                            const void* f1, const void* f2, const int* flag,
                            const bf16* __restrict__ Wt, const float* __restrict__ wbf,
                            bf16* __restrict__ z, int N, int n, int npad)
{
    bool f32 = flag[0] != 0;
    __shared__ __align__(16) char smem[5120 + 16640];
    int tid = threadIdx.x, lane = tid & 63, wv = tid >> 6;
    int quad = lane >> 4, col = lane & 15;
    bf16* ybf = (bf16*)smem + wv * 640;              // per-wave [16][40]
    bf16* Pt = (bf16*)(smem + 5120) + wv * 1152;     // per-wave [16][72]
    float* zb = (float*)(smem + 5120);               // block [64][65] (overlays Pt, after barrier)

    int row0 = blockIdx.x * 64;                      // N % 64 == 0
    int b = row0 / N;
    int pix0 = row0 - b * N;

    short8 ta = *(const short8*)(theta + (size_t)(row0 + wv * 16 + col) * 32 + quad * 8);
    const bf16* php = phiB + (size_t)b * npad * 32 + (size_t)col * 32 + quad * 8;
    const bf16* gtp = gT + (size_t)b * 32 * npad + (size_t)col * npad + quad * 8;

    floatx4 y0 = {0.f, 0.f, 0.f, 0.f}, y1 = {0.f, 0.f, 0.f, 0.f};
    float lp[4] = {0.f, 0.f, 0.f, 0.f};
    const floatx4 zc = {0.f, 0.f, 0.f, 0.f};

    for (int j0 = 0; j0 < npad; j0 += 64) {
        floatx4 s0 = MFMA16(ta, *(const short8*)(php + (size_t)(j0 +  0) * 32), zc);
        floatx4 s1 = MFMA16(ta, *(const short8*)(php + (size_t)(j0 + 16) * 32), zc);
        floatx4 s2 = MFMA16(ta, *(const short8*)(php + (size_t)(j0 + 32) * 32), zc);
        floatx4 s3 = MFMA16(ta, *(const short8*)(php + (size_t)(j0 + 48) * 32), zc);
#pragma unroll
        for (int r = 0; r < 4; r++) {
            float p0 = __expf(s0[r]), p1 = __expf(s1[r]);
            float p2 = __expf(s2[r]), p3 = __expf(s3[r]);
            lp[r] += (p0 + p1) + (p2 + p3);
            bf16* pr = Pt + (quad * 4 + r) * 72;
            pr[ 0 + col] = f2b(p0);
            pr[16 + col] = f2b(p1);
            pr[32 + col] = f2b(p2);
            pr[48 + col] = f2b(p3);
        }
#pragma unroll
        for (int kc = 0; kc < 2; kc++) {
            short8 pa = *(const short8*)(Pt + col * 72 + kc * 32 + quad * 8);
            short8 g0 = *(const short8*)(gtp + j0 + kc * 32);
            short8 g1 = *(const short8*)(gtp + (size_t)16 * npad + j0 + kc * 32);
            y0 = MFMA16(pa, g0, y0);
            y1 = MFMA16(pa, g1, y1);
        }
    }

    // row sums: reduce lp over the 16 lanes of each quad group, subtract padding
    float linv[4];
#pragma unroll
    for (int r = 0; r < 4; r++) {
        float v = lp[r];
        v += __shfl_xor(v, 1); v += __shfl_xor(v, 2);
        v += __shfl_xor(v, 4); v += __shfl_xor(v, 8);
        linv[r] = 1.f / (v - (float)(npad - n));
    }
    // normalized y -> per-wave LDS [16][40] bf16
#pragma unroll
    for (int r = 0; r < 4; r++) {
        ybf[(quad * 4 + r) * 40 + col] = f2b(y0[r] * linv[r]);
        ybf[(quad * 4 + r) * 40 + 16 + col] = f2b(y1[r] * linv[r]);
    }
    // W-conv via MFMA: zt[ot] = y(16x32) * W(32x16)
    short8 ya = *(const short8*)(ybf + col * 40 + quad * 8);
    floatx4 zt[4];
#pragma unroll
    for (int ot = 0; ot < 4; ot++) {
        short8 wbv = *(const short8*)(Wt + (size_t)(ot * 16 + col) * 32 + quad * 8);
        zt[ot] = MFMA16(ya, wbv, zc);
    }
    __syncthreads();   // all waves done with Pt before zb overlays it
#pragma unroll
    for (int ot = 0; ot < 4; ot++)
#pragma unroll
        for (int r = 0; r < 4; r++)
            zb[(wv * 16 + quad * 4 + r) * 65 + ot * 16 + col] = zt[ot][r];
    __syncthreads();

    // final: lane = pixel, wave owns 16 output channels; coalesced residual+store
    const void* fx = (wv < 2) ? f1 : f2;
#pragma unroll
    for (int k = 0; k < 16; k++) {
        int o = wv * 16 + k, op = o & 31;
        float a = zb[lane * 65 + o] + wbf[o];
        a += ldv(fx, (size_t)(b * 32 + op) * N + pix0 + lane, f32);
        z[((size_t)(b * 64 + o)) * N + pix0 + lane] = f2b(a);
    }
}

// ---------------- K5: 3x3 conv (64->32) + folded BN (proven) ----------------
__launch_bounds__(256)
__global__ void k_conv3(const bf16* __restrict__ z, const float* __restrict__ wfold,
                        const float* __restrict__ bfold, void* out, size_t outOff,
                        const int* flag, int H, int tX)
{
    bool f32 = flag[0] != 0;
    __shared__ float zs[16 * 324];
    const int W = H, Npix = H * W;
    int tid = threadIdx.x;
    int tilesPerImg = tX * tX;
    int b = blockIdx.x / tilesPerImg;
    int t = blockIdx.x % tilesPerImg;
    int ty = t / tX, tx = t % tX;
    int ly = tid >> 4, lx = tid & 15;
    int oy = ty * 16 + ly, ox = tx * 16 + lx;
    bool act = (oy < H) && (ox < W);
    float acc[32];
#pragma unroll
    for (int o = 0; o < 32; o++) acc[o] = 0.f;

    for (int cc = 0; cc < 4; cc++) {
        __syncthreads();
        for (int e = tid; e < 16 * 324; e += 256) {
            int c = e / 324, r = e % 324, yy = r / 18, xx = r % 18;
            int gy = ty * 16 - 1 + yy, gx = tx * 16 - 1 + xx;
            float v = 0.f;
            if (gy >= 0 && gy < H && gx >= 0 && gx < W)
                v = b2f(z[((size_t)(b * 64 + cc * 16 + c)) * Npix + gy * W + gx]);
            zs[e] = v;
        }
        __syncthreads();
        if (act) {
            for (int c = 0; c < 16; c++) {
#pragma unroll
                for (int dy = 0; dy < 3; dy++)
#pragma unroll
                    for (int dx = 0; dx < 3; dx++) {
                        float zv = zs[c * 324 + (ly + dy) * 18 + (lx + dx)];
                        const float* w = wfold + ((size_t)(cc * 16 + c) * 9 + dy * 3 + dx) * 32;
#pragma unroll
                        for (int o = 0; o < 32; o++) acc[o] += zv * w[o];
                    }
            }
        }
    }
    if (act) {
        size_t ob = outOff + (size_t)b * 32 * Npix + (size_t)oy * W + ox;
        if (f32) {
            float* op = (float*)out;
#pragma unroll
            for (int o = 0; o < 32; o++) op[ob + (size_t)o * Npix] = acc[o] + bfold[o];
        } else {
            bf16* op = (bf16*)out;
#pragma unroll
            for (int o = 0; o < 32; o++) op[ob + (size_t)o * Npix] = f2b(acc[o] + bfold[o]);
        }
    }
}

extern "C" void kernel_launch(void* const* d_in, const int* in_sizes, int n_in,
                              void* d_out, int out_size, void* d_ws, size_t ws_size,
                              hipStream_t stream)
{
    const int B = 4;
    const int Hs[3] = {96, 48, 24};
    const int ss[3] = {2, 4, 8};
    const int npads[3] = {2304, 192, 64};
    const size_t outOff[3] = {0, 1179648, 1474560};

    int* flag = (int*)d_ws;
    float* wsf = (float*)d_ws + 16;
    // 3 per-level weight regions of LVS floats each, then bf16 region
    bf16* bb = (bf16*)(wsf + 3 * LVS);               // 16B-aligned
    const size_t BN1 = (size_t)B * 9216;
    size_t o_th = 0;
    size_t o_g = o_th + BN1 * 32;                    // z (BN*64) overlays g+p
    size_t o_p = o_g + BN1 * 32;
    size_t o_phi = o_p + BN1 * 32;                   // B*2304*32
    size_t o_gt = o_phi + (size_t)B * 2304 * 32;
    // total ws ~ 0.31 MB + 8.26 MB

    k_detect<<<1, 256, 0, stream>>>(d_in[0], flag);

    Ptrs hp;
    for (int i = 0; i < 45 && i < n_in; i++) hp.p[i] = d_in[i];
    k_prep<<<dim3(8, 3), 256, 0, stream>>>(hp, flag, wsf);

    for (int lv = 0; lv < 3; lv++) {
        int H = Hs[lv], W = H, N = H * W, s = ss[lv];
        int wp = W / s, n = wp * wp, npad = npads[lv];
        const void* f1 = d_in[2 * lv];
        const void* f2 = d_in[2 * lv + 1];
        float* base = wsf + (size_t)lv * LVS;
        int BN = B * N;
        k_tgp<<<dim3(BN / 256, 3), 256, 0, stream>>>(f1, f2, flag,
                                                     base + O_WTGP, base + O_BTGP,
                                                     bb + o_th, bb + o_g, bb + o_p, N);
        int tot = B * npad * 32;
        k_pool<<<(tot + 255) / 256, 256, 0, stream>>>(bb + o_g, bb + o_p,
                                                      bb + o_phi, bb + o_gt,
                                                      n, npad, W, s, wp, tot);
        k_attn_mfma<<<BN / 64, 256, 0, stream>>>(bb + o_th, bb + o_phi, bb + o_gt,
                                                 f1, f2, flag,
                                                 (const bf16*)(base + O_WT), base + O_WBF,
                                                 bb + o_g, N, n, npad);   // z overlays g/p
        int tX = (H + 15) / 16;
        k_conv3<<<B * tX * tX, 256, 0, stream>>>(bb + o_g, base + O_WFOLD, base + O_BFOLD,
                                                 d_out, outOff[lv], flag, H, tX);
    }
}

// Round 6
// 472.681 us; speedup vs baseline: 3.2813x; 1.5514x over previous
//
#include <hip/hip_runtime.h>
#include <hip/hip_bf16.h>

typedef __hip_bfloat16 bf16;
typedef __attribute__((ext_vector_type(8))) short short8;
typedef __attribute__((ext_vector_type(4))) float floatx4;

__device__ __forceinline__ float b2f(bf16 v) { return __bfloat162float(v); }
__device__ __forceinline__ bf16 f2b(float v) { return __float2bfloat16(v); }
__device__ __forceinline__ float ldv(const void* p, size_t i, bool f32) {
    return f32 ? ((const float*)p)[i] : b2f(((const bf16*)p)[i]);
}
#define MFMA16(a, b, c) __builtin_amdgcn_mfma_f32_16x16x32_bf16(a, b, c, 0, 0, 0)

struct Ptrs { const void* p[45]; };

// ---------------- K-1: dtype detector (proven) ----------------
__global__ void k_detect(const void* x, int* flag) {
    __shared__ int cnt;
    if (threadIdx.x == 0) cnt = 0;
    __syncthreads();
    const unsigned short* us = (const unsigned short*)x;
    int local = 0;
    for (int i = threadIdx.x; i < 8192; i += 256) {
        unsigned e = us[2 * i] & 0x7F80u;
        if (e == 0x7F80u || e == 0u) local++;
    }
    atomicAdd(&cnt, local);
    __syncthreads();
    if (threadIdx.x == 0) flag[0] = (cnt >= 8) ? 1 : 0;
}

// per-level weight region layout (float offsets), stride LVS
#define O_WTGP  0
#define O_BTGP  6144
#define O_WBF   6240
#define O_BFOLD 6304
#define O_WT    6336            // 2048 bf16 = 1024 floats
#define O_WC3   7360            // 18432 bf16 = 9216 floats
#define LVS     16576

// ---------------- K0: fused weight prep, all 3 levels ----------------
__global__ void k_prep(Ptrs in, const int* flag, float* __restrict__ wsf)
{
    int lv = blockIdx.y;
    float* base = wsf + (size_t)lv * LVS;
    const int wb0 = 6 + 13 * lv;
    const void* gw  = in.p[wb0 + 0];
    const void* gb  = in.p[wb0 + 1];
    const void* tw  = in.p[wb0 + 2];
    const void* tb  = in.p[wb0 + 3];
    const void* pw  = in.p[wb0 + 4];
    const void* pb  = in.p[wb0 + 5];
    const void* ww  = in.p[wb0 + 6];
    const void* wb  = in.p[wb0 + 7];
    const void* cw  = in.p[wb0 + 8];
    const void* bng = in.p[wb0 + 9];
    const void* bnb = in.p[wb0 + 10];
    const void* bnm = in.p[wb0 + 11];
    const void* bnv = in.p[wb0 + 12];
    bool f32 = flag[0] != 0;
    int gid = blockIdx.x * 256 + threadIdx.x;
    int stride = gridDim.x * 256;

    float* wtgp = base + O_WTGP;
    float* btgp = base + O_BTGP;
    float* wbf = base + O_WBF;
    float* bfold = base + O_BFOLD;
    bf16* Wt = (bf16*)(base + O_WT);
    bf16* Wc3 = (bf16*)(base + O_WC3);

    // wtgp[k][96]: cols [theta 0..31 | g 32..63 | phi 64..95]
    for (int e = gid; e < 64 * 96; e += stride) {
        int k = e / 96, c = e % 96;
        float v;
        if (c < 32)      v = ldv(tw, (size_t)c * 64 + k, f32);
        else if (c < 64) v = ldv(gw, (size_t)(c - 32) * 64 + k, f32);
        else             v = ldv(pw, (size_t)(c - 64) * 64 + k, f32);
        wtgp[e] = v;
    }
    for (int e = gid; e < 96; e += stride) {
        float v = (e < 32) ? ldv(tb, e, f32)
                           : (e < 64 ? ldv(gb, e - 32, f32) : ldv(pb, e - 64, f32));
        btgp[e] = v;
    }
    // Wt[o][c] bf16: B-frag layout for W 1x1 conv (validated)
    for (int e = gid; e < 64 * 32; e += stride)
        Wt[e] = f2b(ldv(ww, e, f32));
    for (int e = gid; e < 64; e += stride) wbf[e] = ldv(wb, e, f32);
    // Wc3: B-frag layout for 3x3 conv, BN-folded:
    // e = ((cc*9+tap)*2+ot)*512 + n*32 + k ; value = cw[o][c][tap]*inv[o],
    // o = ot*16+n, c = cc*32+k
    for (int e = gid; e < 18432; e += stride) {
        int k = e & 31, n = (e >> 5) & 15, ot = (e >> 9) & 1;
        int tap = (e >> 10) % 9, cc = e / 9216;
        int o = ot * 16 + n, c = cc * 32 + k;
        float inv = ldv(bng, o, f32) * rsqrtf(ldv(bnv, o, f32) + 1e-5f);
        Wc3[e] = f2b(ldv(cw, ((size_t)o * 64 + c) * 9 + tap, f32) * inv);
    }
    for (int e = gid; e < 32; e += stride) {
        float inv = ldv(bng, e, f32) * rsqrtf(ldv(bnv, e, f32) + 1e-5f);
        bfold[e] = ldv(bnb, e, f32) - ldv(bnm, e, f32) * inv;
    }
}

// ---------------- K1: theta/g/phi 1x1 conv; blockIdx.y = output group (proven) ----------------
__global__ void k_tgp(const void* f1, const void* f2, const int* flag,
                      const float* __restrict__ wtgp, const float* __restrict__ btgp,
                      bf16* __restrict__ theta, bf16* __restrict__ gfull,
                      bf16* __restrict__ pfull, int N)
{
    bool f32 = flag[0] != 0;
    int grp = blockIdx.y;
    bf16* dst = (grp == 0) ? theta : ((grp == 1) ? gfull : pfull);
    int co = grp * 32;
    int gid = blockIdx.x * 256 + threadIdx.x;
    int b = gid / N;
    int ii = gid - b * N;
    float acc[32];
#pragma unroll
    for (int c = 0; c < 32; c++) acc[c] = btgp[co + c];
    size_t base = (size_t)b * 32 * N + ii;
    for (int k = 0; k < 32; k++) {
        float xv = ldv(f1, base + (size_t)k * N, f32);
        const float* w = wtgp + k * 96 + co;
#pragma unroll
        for (int c = 0; c < 32; c++) acc[c] += xv * w[c];
    }
    for (int k = 0; k < 32; k++) {
        float xv = ldv(f2, base + (size_t)k * N, f32);
        const float* w = wtgp + (k + 32) * 96 + co;
#pragma unroll
        for (int c = 0; c < 32; c++) acc[c] += xv * w[c];
    }
    bf16* dp = dst + (size_t)gid * 32;
#pragma unroll
    for (int c = 0; c < 32; c++) dp[c] = f2b(acc[c]);
}

// ---------------- K2: max pool -> phiB[b][npad][32], gT[b][32][npad] (proven) ----------------
__global__ void k_pool(const bf16* __restrict__ gfull, const bf16* __restrict__ pfull,
                       bf16* __restrict__ phiB, bf16* __restrict__ gT,
                       int n, int npad, int W, int s, int wp, int total)
{
    int gid = blockIdx.x * 256 + threadIdx.x;
    if (gid >= total) return;
    int c = gid & 31;
    int j = (gid >> 5) % npad;
    int b = gid / (32 * npad);
    float mg = 0.f, mp = 0.f;
    if (j < n) {
        int py = j / wp, px = j % wp;
        const int N = W * W;
        mg = -INFINITY; mp = -INFINITY;
        for (int dy = 0; dy < s; dy++)
            for (int dx = 0; dx < s; dx++) {
                int idx = (py * s + dy) * W + px * s + dx;
                size_t bse = ((size_t)b * N + idx) * 32 + c;
                mg = fmaxf(mg, b2f(gfull[bse]));
                mp = fmaxf(mp, b2f(pfull[bse]));
            }
    }
    phiB[((size_t)b * npad + j) * 32 + c] = f2b(mp);
    gT[((size_t)b * 32 + c) * npad + j] = f2b(mg);
}

// ---------------- K3: MFMA attention + W-conv + residual (proven this round) ----------------
__launch_bounds__(256)
__global__ void k_attn_mfma(const bf16* __restrict__ theta, const bf16* __restrict__ phiB,
                            const bf16* __restrict__ gT,
                            const void* f1, const void* f2, const int* flag,
                            const bf16* __restrict__ Wt, const float* __restrict__ wbf,
                            bf16* __restrict__ z, int N, int n, int npad)
{
    bool f32 = flag[0] != 0;
    __shared__ __align__(16) char smem[5120 + 16640];
    int tid = threadIdx.x, lane = tid & 63, wv = tid >> 6;
    int quad = lane >> 4, col = lane & 15;
    bf16* ybf = (bf16*)smem + wv * 640;
    bf16* Pt = (bf16*)(smem + 5120) + wv * 1152;
    float* zb = (float*)(smem + 5120);

    int row0 = blockIdx.x * 64;
    int b = row0 / N;
    int pix0 = row0 - b * N;

    short8 ta = *(const short8*)(theta + (size_t)(row0 + wv * 16 + col) * 32 + quad * 8);
    const bf16* php = phiB + (size_t)b * npad * 32 + (size_t)col * 32 + quad * 8;
    const bf16* gtp = gT + (size_t)b * 32 * npad + (size_t)col * npad + quad * 8;

    floatx4 y0 = {0.f, 0.f, 0.f, 0.f}, y1 = {0.f, 0.f, 0.f, 0.f};
    float lp[4] = {0.f, 0.f, 0.f, 0.f};
    const floatx4 zc = {0.f, 0.f, 0.f, 0.f};

    for (int j0 = 0; j0 < npad; j0 += 64) {
        floatx4 s0 = MFMA16(ta, *(const short8*)(php + (size_t)(j0 +  0) * 32), zc);
        floatx4 s1 = MFMA16(ta, *(const short8*)(php + (size_t)(j0 + 16) * 32), zc);
        floatx4 s2 = MFMA16(ta, *(const short8*)(php + (size_t)(j0 + 32) * 32), zc);
        floatx4 s3 = MFMA16(ta, *(const short8*)(php + (size_t)(j0 + 48) * 32), zc);
#pragma unroll
        for (int r = 0; r < 4; r++) {
            float p0 = __expf(s0[r]), p1 = __expf(s1[r]);
            float p2 = __expf(s2[r]), p3 = __expf(s3[r]);
            lp[r] += (p0 + p1) + (p2 + p3);
            bf16* pr = Pt + (quad * 4 + r) * 72;
            pr[ 0 + col] = f2b(p0);
            pr[16 + col] = f2b(p1);
            pr[32 + col] = f2b(p2);
            pr[48 + col] = f2b(p3);
        }
#pragma unroll
        for (int kc = 0; kc < 2; kc++) {
            short8 pa = *(const short8*)(Pt + col * 72 + kc * 32 + quad * 8);
            short8 g0 = *(const short8*)(gtp + j0 + kc * 32);
            short8 g1 = *(const short8*)(gtp + (size_t)16 * npad + j0 + kc * 32);
            y0 = MFMA16(pa, g0, y0);
            y1 = MFMA16(pa, g1, y1);
        }
    }

    float linv[4];
#pragma unroll
    for (int r = 0; r < 4; r++) {
        float v = lp[r];
        v += __shfl_xor(v, 1); v += __shfl_xor(v, 2);
        v += __shfl_xor(v, 4); v += __shfl_xor(v, 8);
        linv[r] = 1.f / (v - (float)(npad - n));
    }
#pragma unroll
    for (int r = 0; r < 4; r++) {
        ybf[(quad * 4 + r) * 40 + col] = f2b(y0[r] * linv[r]);
        ybf[(quad * 4 + r) * 40 + 16 + col] = f2b(y1[r] * linv[r]);
    }
    short8 ya = *(const short8*)(ybf + col * 40 + quad * 8);
    floatx4 zt[4];
#pragma unroll
    for (int ot = 0; ot < 4; ot++) {
        short8 wbv = *(const short8*)(Wt + (size_t)(ot * 16 + col) * 32 + quad * 8);
        zt[ot] = MFMA16(ya, wbv, zc);
    }
    __syncthreads();
#pragma unroll
    for (int ot = 0; ot < 4; ot++)
#pragma unroll
        for (int r = 0; r < 4; r++)
            zb[(wv * 16 + quad * 4 + r) * 65 + ot * 16 + col] = zt[ot][r];
    __syncthreads();

    const void* fx = (wv < 2) ? f1 : f2;
#pragma unroll
    for (int k = 0; k < 16; k++) {
        int o = wv * 16 + k, op = o & 31;
        float a = zb[lane * 65 + o] + wbf[o];
        a += ldv(fx, (size_t)(b * 32 + op) * N + pix0 + lane, f32);
        z[((size_t)(b * 64 + o)) * N + pix0 + lane] = f2b(a);
    }
}

// ---------------- K5: MFMA 3x3 conv (64->32) + folded BN ----------------
// 16x16 pixel tile/block; halo 18x18 staged per 32-ch chunk as [pix][32+2pad] bf16.
// Per wave: 4 pixel-rows; per tap: A-frag = shifted halo read, 2 MFMA (2 out-tiles).
__launch_bounds__(256)
__global__ void k_conv3m(const bf16* __restrict__ z, const bf16* __restrict__ Wc3,
                         const float* __restrict__ bfold, void* out, size_t outOff,
                         const int* flag, int H, int tX)
{
    bool f32 = flag[0] != 0;
    __shared__ __align__(16) bf16 zh[324 * 34];   // 22,032 B
    const int W = H, Npix = H * W;
    int tid = threadIdx.x, lane = tid & 63, wv = tid >> 6;
    int quad = lane >> 4, col = lane & 15;
    int tpi = tX * tX;
    int b = blockIdx.x / tpi;
    int t = blockIdx.x % tpi;
    int ty = t / tX, tx = t % tX;
    int y0 = ty * 16, x0 = tx * 16;

    floatx4 acc[4][2];
#pragma unroll
    for (int pt = 0; pt < 4; pt++)
#pragma unroll
        for (int ot = 0; ot < 2; ot++) acc[pt][ot] = (floatx4){0.f, 0.f, 0.f, 0.f};

    for (int cc = 0; cc < 2; cc++) {
        __syncthreads();
        for (int e = tid; e < 324 * 32; e += 256) {
            int c = e / 324, pix = e - c * 324;
            int hy = pix / 18, hx = pix - hy * 18;
            int gy = y0 - 1 + hy, gx = x0 - 1 + hx;
            bf16 v = f2b(0.f);
            if (gy >= 0 && gy < H && gx >= 0 && gx < W)
                v = z[((size_t)(b * 64 + cc * 32 + c)) * Npix + gy * W + gx];
            zh[pix * 34 + c] = v;
        }
        __syncthreads();
        // preload 18 B-frags (9 taps x 2 out-tiles) for this cc chunk
        short8 Bf[9][2];
        const bf16* wp = Wc3 + (size_t)cc * 9216 + col * 32 + quad * 8;
#pragma unroll
        for (int tap = 0; tap < 9; tap++) {
#pragma unroll
            for (int ot = 0; ot < 2; ot++)
                Bf[tap][ot] = *(const short8*)(wp + (tap * 2 + ot) * 512);
        }
#pragma unroll
        for (int pt = 0; pt < 4; pt++) {
            int yy = wv * 4 + pt;
#pragma unroll
            for (int tap = 0; tap < 9; tap++) {
                int dy = tap / 3, dx = tap - dy * 3;
                short8 A = *(const short8*)(zh + ((yy + dy) * 18 + (col + dx)) * 34 + quad * 8);
                acc[pt][0] = MFMA16(A, Bf[tap][0], acc[pt][0]);
                acc[pt][1] = MFMA16(A, Bf[tap][1], acc[pt][1]);
            }
        }
    }
    // store: lane holds pixel x = quad*4+r (m), out channel o = ot*16+col (n)
#pragma unroll
    for (int pt = 0; pt < 4; pt++) {
        int oy = y0 + wv * 4 + pt;
        if (oy >= H) continue;
#pragma unroll
        for (int ot = 0; ot < 2; ot++) {
            int o = ot * 16 + col;
            size_t ob = outOff + (size_t)(b * 32 + o) * Npix + (size_t)oy * W;
            float bias = bfold[o];
#pragma unroll
            for (int r = 0; r < 4; r++) {
                int ox = x0 + quad * 4 + r;
                if (ox >= W) continue;
                float a = acc[pt][ot][r] + bias;
                if (f32) ((float*)out)[ob + ox] = a;
                else     ((bf16*)out)[ob + ox] = f2b(a);
            }
        }
    }
}

extern "C" void kernel_launch(void* const* d_in, const int* in_sizes, int n_in,
                              void* d_out, int out_size, void* d_ws, size_t ws_size,
                              hipStream_t stream)
{
    const int B = 4;
    const int Hs[3] = {96, 48, 24};
    const int ss[3] = {2, 4, 8};
    const int npads[3] = {2304, 192, 64};
    const size_t outOff[3] = {0, 1179648, 1474560};

    int* flag = (int*)d_ws;
    float* wsf = (float*)d_ws + 16;
    bf16* bb = (bf16*)(wsf + 3 * LVS);
    const size_t BN1 = (size_t)B * 9216;
    size_t o_th = 0;
    size_t o_g = o_th + BN1 * 32;                    // z (BN*64) overlays g+p
    size_t o_p = o_g + BN1 * 32;
    size_t o_phi = o_p + BN1 * 32;
    size_t o_gt = o_phi + (size_t)B * 2304 * 32;

    k_detect<<<1, 256, 0, stream>>>(d_in[0], flag);

    Ptrs hp;
    for (int i = 0; i < 45 && i < n_in; i++) hp.p[i] = d_in[i];
    k_prep<<<dim3(8, 3), 256, 0, stream>>>(hp, flag, wsf);

    for (int lv = 0; lv < 3; lv++) {
        int H = Hs[lv], W = H, N = H * W, s = ss[lv];
        int wp = W / s, n = wp * wp, npad = npads[lv];
        const void* f1 = d_in[2 * lv];
        const void* f2 = d_in[2 * lv + 1];
        float* base = wsf + (size_t)lv * LVS;
        int BN = B * N;
        k_tgp<<<dim3(BN / 256, 3), 256, 0, stream>>>(f1, f2, flag,
                                                     base + O_WTGP, base + O_BTGP,
                                                     bb + o_th, bb + o_g, bb + o_p, N);
        int tot = B * npad * 32;
        k_pool<<<(tot + 255) / 256, 256, 0, stream>>>(bb + o_g, bb + o_p,
                                                      bb + o_phi, bb + o_gt,
                                                      n, npad, W, s, wp, tot);
        k_attn_mfma<<<BN / 64, 256, 0, stream>>>(bb + o_th, bb + o_phi, bb + o_gt,
                                                 f1, f2, flag,
                                                 (const bf16*)(base + O_WT), base + O_WBF,
                                                 bb + o_g, N, n, npad);   // z overlays g/p
        int tX = (H + 15) / 16;
        k_conv3m<<<B * tX * tX, 256, 0, stream>>>(bb + o_g, (const bf16*)(base + O_WC3),
                                                  base + O_BFOLD, d_out, outOff[lv],
                                                  flag, H, tX);
    }
}

// Round 7
// 320.013 us; speedup vs baseline: 4.8467x; 1.4771x over previous
//
#include <hip/hip_runtime.h>
#include <hip/hip_bf16.h>

typedef __hip_bfloat16 bf16;
typedef __attribute__((ext_vector_type(8))) short short8;
typedef __attribute__((ext_vector_type(4))) float floatx4;

__device__ __forceinline__ float b2f(bf16 v) { return __bfloat162float(v); }
__device__ __forceinline__ bf16 f2b(float v) { return __float2bfloat16(v); }
__device__ __forceinline__ float ldv(const void* p, size_t i, bool f32) {
    return f32 ? ((const float*)p)[i] : b2f(((const bf16*)p)[i]);
}
__device__ __forceinline__ float s2f(short s) {
    unsigned int u = ((unsigned int)(unsigned short)s) << 16;
    float f; __builtin_memcpy(&f, &u, 4); return f;
}
__device__ __forceinline__ short f2s(float f) {
    bf16 h = f2b(f); short s; __builtin_memcpy(&s, &h, 2); return s;
}
#define MFMA16(a, b, c) __builtin_amdgcn_mfma_f32_16x16x32_bf16(a, b, c, 0, 0, 0)

struct Ptrs { const void* p[45]; };

// Per-level parameter pack for fused (all-levels-in-one-launch) kernels.
struct Lvl {
    const void *f1, *f2;
    const float *wtgp, *btgp, *wbf, *bfold;
    const bf16 *Wt, *Wc3;
    bf16 *th, *g, *p, *phi, *gt, *yp, *z;
    float* lp;
    int N, n, npad, split, W, s, wp, H, tX, BN;
    size_t outOff;
};

// ---------------- K-1: dtype detector (proven) ----------------
__global__ void k_detect(const void* x, int* flag) {
    __shared__ int cnt;
    if (threadIdx.x == 0) cnt = 0;
    __syncthreads();
    const unsigned short* us = (const unsigned short*)x;
    int local = 0;
    for (int i = threadIdx.x; i < 8192; i += 256) {
        unsigned e = us[2 * i] & 0x7F80u;
        if (e == 0x7F80u || e == 0u) local++;
    }
    atomicAdd(&cnt, local);
    __syncthreads();
    if (threadIdx.x == 0) flag[0] = (cnt >= 8) ? 1 : 0;
}

// per-level weight region layout (float offsets), stride LVS
#define O_WTGP  0
#define O_BTGP  6144
#define O_WBF   6240
#define O_BFOLD 6304
#define O_WT    6336
#define O_WC3   7360
#define LVS     16576

// ---------------- K0: fused weight prep (proven R6) ----------------
__global__ void k_prep(Ptrs in, const int* flag, float* __restrict__ wsf)
{
    int lv = blockIdx.y;
    float* base = wsf + (size_t)lv * LVS;
    const int wb0 = 6 + 13 * lv;
    const void* gw  = in.p[wb0 + 0];
    const void* gb  = in.p[wb0 + 1];
    const void* tw  = in.p[wb0 + 2];
    const void* tb  = in.p[wb0 + 3];
    const void* pw  = in.p[wb0 + 4];
    const void* pb  = in.p[wb0 + 5];
    const void* ww  = in.p[wb0 + 6];
    const void* wb  = in.p[wb0 + 7];
    const void* cw  = in.p[wb0 + 8];
    const void* bng = in.p[wb0 + 9];
    const void* bnb = in.p[wb0 + 10];
    const void* bnm = in.p[wb0 + 11];
    const void* bnv = in.p[wb0 + 12];
    bool f32 = flag[0] != 0;
    int gid = blockIdx.x * 256 + threadIdx.x;
    int stride = gridDim.x * 256;

    float* wtgp = base + O_WTGP;
    float* btgp = base + O_BTGP;
    float* wbf = base + O_WBF;
    float* bfold = base + O_BFOLD;
    bf16* Wt = (bf16*)(base + O_WT);
    bf16* Wc3 = (bf16*)(base + O_WC3);

    for (int e = gid; e < 64 * 96; e += stride) {
        int k = e / 96, c = e % 96;
        float v;
        if (c < 32)      v = ldv(tw, (size_t)c * 64 + k, f32);
        else if (c < 64) v = ldv(gw, (size_t)(c - 32) * 64 + k, f32);
        else             v = ldv(pw, (size_t)(c - 64) * 64 + k, f32);
        wtgp[e] = v;
    }
    for (int e = gid; e < 96; e += stride) {
        float v = (e < 32) ? ldv(tb, e, f32)
                           : (e < 64 ? ldv(gb, e - 32, f32) : ldv(pb, e - 64, f32));
        btgp[e] = v;
    }
    for (int e = gid; e < 64 * 32; e += stride)
        Wt[e] = f2b(ldv(ww, e, f32));
    for (int e = gid; e < 64; e += stride) wbf[e] = ldv(wb, e, f32);
    for (int e = gid; e < 18432; e += stride) {
        int k = e & 31, n = (e >> 5) & 15, ot = (e >> 9) & 1;
        int tap = (e >> 10) % 9, cc = e / 9216;
        int o = ot * 16 + n, c = cc * 32 + k;
        float inv = ldv(bng, o, f32) * rsqrtf(ldv(bnv, o, f32) + 1e-5f);
        Wc3[e] = f2b(ldv(cw, ((size_t)o * 64 + c) * 9 + tap, f32) * inv);
    }
    for (int e = gid; e < 32; e += stride) {
        float inv = ldv(bng, e, f32) * rsqrtf(ldv(bnv, e, f32) + 1e-5f);
        bfold[e] = ldv(bnb, e, f32) - ldv(bnm, e, f32) * inv;
    }
}

// ---------------- K1: theta/g/phi 1x1 conv, fused over levels ----------------
__global__ void k_tgp(Lvl a0, Lvl a1, Lvl a2, int s1, int s2, const int* flag)
{
    bool f32 = flag[0] != 0;
    int bid = blockIdx.x;
    const Lvl P = bid < s1 ? a0 : (bid < s2 ? a1 : a2);
    int local = bid - (bid < s1 ? 0 : (bid < s2 ? s1 : s2));
    int nbp = P.BN >> 8;
    int grp = local / nbp;
    int pb = local - grp * nbp;
    bf16* dst = (grp == 0) ? P.th : ((grp == 1) ? P.g : P.p);
    int co = grp * 32;
    int gid = pb * 256 + threadIdx.x;
    int N = P.N;
    int b = gid / N;
    int ii = gid - b * N;
    float acc[32];
#pragma unroll
    for (int c = 0; c < 32; c++) acc[c] = P.btgp[co + c];
    size_t base = (size_t)b * 32 * N + ii;
    for (int k = 0; k < 32; k++) {
        float xv = ldv(P.f1, base + (size_t)k * N, f32);
        const float* w = P.wtgp + k * 96 + co;
#pragma unroll
        for (int c = 0; c < 32; c++) acc[c] += xv * w[c];
    }
    for (int k = 0; k < 32; k++) {
        float xv = ldv(P.f2, base + (size_t)k * N, f32);
        const float* w = P.wtgp + (k + 32) * 96 + co;
#pragma unroll
        for (int c = 0; c < 32; c++) acc[c] += xv * w[c];
    }
    bf16* dp = dst + (size_t)gid * 32;
#pragma unroll
    for (int c = 0; c < 32; c++) dp[c] = f2b(acc[c]);
}

// ---------------- K2: max pool -> phiB / gT, fused over levels ----------------
__global__ void k_pool(Lvl a0, Lvl a1, Lvl a2, int s1, int s2)
{
    int bid = blockIdx.x;
    const Lvl P = bid < s1 ? a0 : (bid < s2 ? a1 : a2);
    int local = bid - (bid < s1 ? 0 : (bid < s2 ? s1 : s2));
    int gid = local * 256 + threadIdx.x;
    int npad = P.npad;
    if (gid >= 4 * npad * 32) return;
    int c = gid & 31;
    int j = (gid >> 5) % npad;
    int b = gid / (32 * npad);
    float mg = 0.f, mp = 0.f;
    if (j < P.n) {
        int py = j / P.wp, px = j - py * P.wp;
        const int N = P.N;
        mg = -INFINITY; mp = -INFINITY;
        for (int dy = 0; dy < P.s; dy++)
            for (int dx = 0; dx < P.s; dx++) {
                int idx = (py * P.s + dy) * P.W + px * P.s + dx;
                size_t bse = ((size_t)b * N + idx) * 32 + c;
                mg = fmaxf(mg, b2f(P.g[bse]));
                mp = fmaxf(mp, b2f(P.p[bse]));
            }
    }
    P.phi[((size_t)b * npad + j) * 32 + c] = f2b(mp);
    P.gt[((size_t)b * 32 + c) * npad + j] = f2b(mg);
}

// ---------------- K3: MFMA attention, key-split partials, fused over levels ----------------
// blockIdx -> (level, chunk c in {0,1}, row-block). Writes UNNORMALIZED y (bf16)
// and row-sums l (fp32); no epilogue here. Empty chunks (L2 c=1) write zeros.
__launch_bounds__(256)
__global__ void k_attn(Lvl a0, Lvl a1, Lvl a2, int s1, int s2)
{
    __shared__ __align__(16) bf16 Pt_s[4 * 1152];
    int bid = blockIdx.x;
    const Lvl P = bid < s1 ? a0 : (bid < s2 ? a1 : a2);
    int local = bid - (bid < s1 ? 0 : (bid < s2 ? s1 : s2));
    int rowblocks = P.BN >> 6;
    int c = local / rowblocks;
    int rb = local - c * rowblocks;

    int tid = threadIdx.x, lane = tid & 63, wv = tid >> 6;
    int quad = lane >> 4, col = lane & 15;
    bf16* Pt = Pt_s + wv * 1152;
    int row0 = rb * 64;
    int b = row0 / P.N;
    int npad = P.npad;

    short8 ta = *(const short8*)(P.th + (size_t)(row0 + wv * 16 + col) * 32 + quad * 8);
    const bf16* php = P.phi + (size_t)b * npad * 32 + (size_t)col * 32 + quad * 8;
    const bf16* gtp = P.gt + (size_t)b * 32 * npad + (size_t)col * npad + quad * 8;

    floatx4 y0 = {0.f, 0.f, 0.f, 0.f}, y1 = {0.f, 0.f, 0.f, 0.f};
    float lp4[4] = {0.f, 0.f, 0.f, 0.f};
    const floatx4 zc = {0.f, 0.f, 0.f, 0.f};

    int js = c ? P.split : 0;
    int je = c ? npad : P.split;
    for (int j0 = js; j0 < je; j0 += 64) {
        floatx4 s0 = MFMA16(ta, *(const short8*)(php + (size_t)(j0 +  0) * 32), zc);
        floatx4 s1 = MFMA16(ta, *(const short8*)(php + (size_t)(j0 + 16) * 32), zc);
        floatx4 s2 = MFMA16(ta, *(const short8*)(php + (size_t)(j0 + 32) * 32), zc);
        floatx4 s3 = MFMA16(ta, *(const short8*)(php + (size_t)(j0 + 48) * 32), zc);
#pragma unroll
        for (int r = 0; r < 4; r++) {
            float p0 = __expf(s0[r]), p1 = __expf(s1[r]);
            float p2 = __expf(s2[r]), p3 = __expf(s3[r]);
            lp4[r] += (p0 + p1) + (p2 + p3);
            bf16* pr = Pt + (quad * 4 + r) * 72;
            pr[ 0 + col] = f2b(p0);
            pr[16 + col] = f2b(p1);
            pr[32 + col] = f2b(p2);
            pr[48 + col] = f2b(p3);
        }
#pragma unroll
        for (int kc = 0; kc < 2; kc++) {
            short8 pa = *(const short8*)(Pt + col * 72 + kc * 32 + quad * 8);
            short8 g0 = *(const short8*)(gtp + j0 + kc * 32);
            short8 g1 = *(const short8*)(gtp + (size_t)16 * npad + j0 + kc * 32);
            y0 = MFMA16(pa, g0, y0);
            y1 = MFMA16(pa, g1, y1);
        }
    }

#pragma unroll
    for (int r = 0; r < 4; r++) {
        float v = lp4[r];
        v += __shfl_xor(v, 1); v += __shfl_xor(v, 2);
        v += __shfl_xor(v, 4); v += __shfl_xor(v, 8);
        int grow = row0 + wv * 16 + quad * 4 + r;
        size_t o = ((size_t)c * P.BN + grow) * 32;
        P.yp[o + col] = f2b(y0[r]);
        P.yp[o + 16 + col] = f2b(y1[r]);
        if (col == 0) P.lp[(size_t)c * P.BN + grow] = v;
    }
}

// ---------------- K4: merge partials + W-conv + residual -> z, fused over levels ----------------
__launch_bounds__(256)
__global__ void k_merge(Lvl a0, Lvl a1, Lvl a2, int s1, int s2, const int* flag)
{
    bool f32 = flag[0] != 0;
    __shared__ __align__(16) float zb[64 * 65];
    int bid = blockIdx.x;
    const Lvl P = bid < s1 ? a0 : (bid < s2 ? a1 : a2);
    int rb = bid - (bid < s1 ? 0 : (bid < s2 ? s1 : s2));
    int tid = threadIdx.x, lane = tid & 63, wv = tid >> 6;
    int quad = lane >> 4, col = lane & 15;
    int row0 = rb * 64;
    int b = row0 / P.N;
    int pix0 = row0 - b * P.N;

    // A-frag: y[row=col][k=quad*8+j] = (yp0+yp1)/L
    int grow = row0 + wv * 16 + col;
    short8 v0 = *(const short8*)(P.yp + (size_t)grow * 32 + quad * 8);
    short8 v1 = *(const short8*)(P.yp + ((size_t)P.BN + grow) * 32 + quad * 8);
    float L = P.lp[grow] + P.lp[(size_t)P.BN + grow] - (float)(P.npad - P.n);
    float invL = 1.f / L;
    short8 ya;
#pragma unroll
    for (int j = 0; j < 8; j++)
        ya[j] = f2s((s2f(v0[j]) + s2f(v1[j])) * invL);

    const floatx4 zc = {0.f, 0.f, 0.f, 0.f};
    floatx4 zt[4];
#pragma unroll
    for (int ot = 0; ot < 4; ot++) {
        short8 wbv = *(const short8*)(P.Wt + (size_t)(ot * 16 + col) * 32 + quad * 8);
        zt[ot] = MFMA16(ya, wbv, zc);
    }
#pragma unroll
    for (int ot = 0; ot < 4; ot++)
#pragma unroll
        for (int r = 0; r < 4; r++)
            zb[(wv * 16 + quad * 4 + r) * 65 + ot * 16 + col] = zt[ot][r];
    __syncthreads();

    const void* fx = (wv < 2) ? P.f1 : P.f2;
#pragma unroll
    for (int k = 0; k < 16; k++) {
        int o = wv * 16 + k, op = o & 31;
        float a = zb[lane * 65 + o] + P.wbf[o];
        a += ldv(fx, (size_t)(b * 32 + op) * P.N + pix0 + lane, f32);
        P.z[((size_t)(b * 64 + o)) * P.N + pix0 + lane] = f2b(a);
    }
}

// ---------------- K5: MFMA 3x3 conv + folded BN, fused over levels (proven body) ----------------
__launch_bounds__(256)
__global__ void k_conv3m(Lvl a0, Lvl a1, Lvl a2, int s1, int s2,
                         void* out, const int* flag)
{
    bool f32 = flag[0] != 0;
    __shared__ __align__(16) bf16 zh[324 * 34];
    int bid = blockIdx.x;
    const Lvl P = bid < s1 ? a0 : (bid < s2 ? a1 : a2);
    int local = bid - (bid < s1 ? 0 : (bid < s2 ? s1 : s2));
    const int H = P.H, W = H, Npix = H * W, tX = P.tX;
    int tid = threadIdx.x, lane = tid & 63, wv = tid >> 6;
    int quad = lane >> 4, col = lane & 15;
    int tpi = tX * tX;
    int b = local / tpi;
    int t = local - b * tpi;
    int ty = t / tX, tx = t - ty * tX;
    int y0 = ty * 16, x0 = tx * 16;

    floatx4 acc[4][2];
#pragma unroll
    for (int pt = 0; pt < 4; pt++)
#pragma unroll
        for (int ot = 0; ot < 2; ot++) acc[pt][ot] = (floatx4){0.f, 0.f, 0.f, 0.f};

    for (int cc = 0; cc < 2; cc++) {
        __syncthreads();
        for (int e = tid; e < 324 * 32; e += 256) {
            int c = e / 324, pix = e - c * 324;
            int hy = pix / 18, hx = pix - hy * 18;
            int gy = y0 - 1 + hy, gx = x0 - 1 + hx;
            bf16 v = f2b(0.f);
            if (gy >= 0 && gy < H && gx >= 0 && gx < W)
                v = P.z[((size_t)(b * 64 + cc * 32 + c)) * Npix + gy * W + gx];
            zh[pix * 34 + c] = v;
        }
        __syncthreads();
        short8 Bf[9][2];
        const bf16* wp = P.Wc3 + (size_t)cc * 9216 + col * 32 + quad * 8;
#pragma unroll
        for (int tap = 0; tap < 9; tap++)
#pragma unroll
            for (int ot = 0; ot < 2; ot++)
                Bf[tap][ot] = *(const short8*)(wp + (tap * 2 + ot) * 512);
#pragma unroll
        for (int pt = 0; pt < 4; pt++) {
            int yy = wv * 4 + pt;
#pragma unroll
            for (int tap = 0; tap < 9; tap++) {
                int dy = tap / 3, dx = tap - dy * 3;
                short8 A = *(const short8*)(zh + ((yy + dy) * 18 + (col + dx)) * 34 + quad * 8);
                acc[pt][0] = MFMA16(A, Bf[tap][0], acc[pt][0]);
                acc[pt][1] = MFMA16(A, Bf[tap][1], acc[pt][1]);
            }
        }
    }
#pragma unroll
    for (int pt = 0; pt < 4; pt++) {
        int oy = y0 + wv * 4 + pt;
        if (oy >= H) continue;
#pragma unroll
        for (int ot = 0; ot < 2; ot++) {
            int o = ot * 16 + col;
            size_t ob = P.outOff + (size_t)(b * 32 + o) * Npix + (size_t)oy * W;
            float bias = P.bfold[o];
#pragma unroll
            for (int r = 0; r < 4; r++) {
                int ox = x0 + quad * 4 + r;
                if (ox >= W) continue;
                float a = acc[pt][ot][r] + bias;
                if (f32) ((float*)out)[ob + ox] = a;
                else     ((bf16*)out)[ob + ox] = f2b(a);
            }
        }
    }
}

extern "C" void kernel_launch(void* const* d_in, const int* in_sizes, int n_in,
                              void* d_out, int out_size, void* d_ws, size_t ws_size,
                              hipStream_t stream)
{
    const int Hs[3] = {96, 48, 24};
    const int ss[3] = {2, 4, 8};
    const int npads[3] = {2304, 192, 64};
    const int splits[3] = {1152, 128, 64};
    const size_t outOff[3] = {0, 1179648, 1474560};

    int* flag = (int*)d_ws;
    float* wsf = (float*)d_ws + 16;
    float* lpbase = wsf + 3 * LVS;                   // 96768 floats
    bf16* bb = (bf16*)(lpbase + 96768);

    // bf16 element offsets (see journal): gp/yp region, th, phi, gT; z overlays th..end
    const size_t o_gp[3] = {0, 2359296, 2949120};            // 2*BN*32 each
    const size_t R_TH = 3096576;
    const size_t o_th[3] = {R_TH, R_TH + 1179648, R_TH + 1474560};
    const size_t R_PHI = 4644864;
    const size_t o_phi[3] = {R_PHI, R_PHI + 294912, R_PHI + 319488};
    const size_t R_GT = 4972544;
    const size_t o_gt[3] = {R_GT, R_GT + 294912, R_GT + 319488};
    const size_t o_z[3] = {R_TH, R_TH + 2359296, R_TH + 2949120}; // z over th/phi/gt/pad
    const size_t o_lp[3] = {0, 73728, 92160};

    k_detect<<<1, 256, 0, stream>>>(d_in[0], flag);

    Ptrs hp;
    for (int i = 0; i < 45 && i < n_in; i++) hp.p[i] = d_in[i];
    k_prep<<<dim3(8, 3), 256, 0, stream>>>(hp, flag, wsf);

    Lvl L[3];
    for (int lv = 0; lv < 3; lv++) {
        int H = Hs[lv], N = H * H;
        float* base = wsf + (size_t)lv * LVS;
        L[lv].f1 = d_in[2 * lv];
        L[lv].f2 = d_in[2 * lv + 1];
        L[lv].wtgp = base + O_WTGP;
        L[lv].btgp = base + O_BTGP;
        L[lv].wbf = base + O_WBF;
        L[lv].bfold = base + O_BFOLD;
        L[lv].Wt = (const bf16*)(base + O_WT);
        L[lv].Wc3 = (const bf16*)(base + O_WC3);
        L[lv].th = bb + o_th[lv];
        L[lv].g = bb + o_gp[lv];
        L[lv].p = bb + o_gp[lv] + (size_t)4 * N * 32;
        L[lv].phi = bb + o_phi[lv];
        L[lv].gt = bb + o_gt[lv];
        L[lv].yp = bb + o_gp[lv];                    // overlays g+p (dead after pool)
        L[lv].z = bb + o_z[lv];
        L[lv].lp = lpbase + o_lp[lv];
        L[lv].N = N;
        L[lv].n = (H / ss[lv]) * (H / ss[lv]);
        L[lv].npad = npads[lv];
        L[lv].split = splits[lv];
        L[lv].W = H;
        L[lv].s = ss[lv];
        L[lv].wp = H / ss[lv];
        L[lv].H = H;
        L[lv].tX = (H + 15) / 16;
        L[lv].BN = 4 * N;
        L[lv].outOff = outOff[lv];
    }

    // fused grids: per-level block counts
    // tgp: 3*(BN/256) = {432,108,27}; pool: 4*npad*32/256 = {1152,96,32}
    // attn: 2*(BN/64) = {1152,288,72}; merge: BN/64 = {576,144,36}
    // conv: 4*tX*tX = {144,36,16}
    k_tgp<<<567, 256, 0, stream>>>(L[0], L[1], L[2], 432, 540, flag);
    k_pool<<<1280, 256, 0, stream>>>(L[0], L[1], L[2], 1152, 1248);
    k_attn<<<1512, 256, 0, stream>>>(L[0], L[1], L[2], 1152, 1440);
    k_merge<<<756, 256, 0, stream>>>(L[0], L[1], L[2], 576, 720, flag);
    k_conv3m<<<196, 256, 0, stream>>>(L[0], L[1], L[2], 144, 180, d_out, flag);
}